// Round 17
// baseline (310.864 us; speedup 1.0000x reference)
//
#include <hip/hip_runtime.h>
#include <hip/hip_bf16.h>
#include <stdint.h>

#define BATCH 4
#define L_SEQ 2048
#define DIM   1024

typedef __bf16 bf16;
typedef __bf16 bf16x4 __attribute__((ext_vector_type(4)));
typedef __bf16 bf16x8 __attribute__((ext_vector_type(8)));
typedef float  f32x4  __attribute__((ext_vector_type(4)));

#define GLDS(src, dst) __builtin_amdgcn_global_load_lds(\
    (const __attribute__((address_space(1))) void*)(src), \
    (__attribute__((address_space(3))) void*)(dst), 16, 0, 0)

// barrier with memory-clobber only (no sched_barrier: m141 lesson)
#define BARX() do { asm volatile("" ::: "memory"); \
                    __builtin_amdgcn_s_barrier(); \
                    asm volatile("" ::: "memory"); } while (0)

#define MFMA16 __builtin_amdgcn_mfma_f32_16x16x32_bf16

// ---------------- fused fp32 -> bf16 convert, grid-stride (2048 blocks) ----------------
__global__ __launch_bounds__(256)
void cvt_all(const float* __restrict__ x,  const float* __restrict__ Wq,
             const float* __restrict__ Wk, const float* __restrict__ Wv,
             bf16* __restrict__ Xb, bf16* __restrict__ Wcat)
{
    for (int b = blockIdx.x; b < 11264; b += 2048) {
        const float* src; bf16* dst; int i;
        if (b < 8192) { src = x; dst = Xb; i = b * 256 + threadIdx.x; }
        else {
            int s = (b - 8192) >> 10;
            src = s == 0 ? Wq : (s == 1 ? Wk : Wv);
            dst = Wcat + (size_t)s * 1048576;
            i = ((b - 8192) & 1023) * 256 + threadIdx.x;
        }
        float4 v = ((const float4*)src)[i];
        bf16x4 o = { (bf16)v.x, (bf16)v.y, (bf16)v.z, (bf16)v.w };
        ((bf16x4*)dst)[i] = o;
    }
}

// ---- 128x128-tile, KB-wide K-step, 4 waves (2x2), 2-barrier counted-vmcnt ----
// KB=64: 64 KB LDS -> 2 blocks/CU (proven R10 path).
// KB=32: 32 KB LDS -> 5 blocks/CU; conflict-free swizzle byte^(((row>>2)&3)<<4).
// A[m][k], B[n][k], K-contiguous; C = A*B^T fp32; A-dim contiguous in output.
// MODE 0: QKV  A=Wcat[3072][1024], B=X[8192][1024]; XCD-chunked grid (1536)
// MODE 2: SC   A=K[2048][1024],    B=Q[2048][1024]; 16x16 tile grid/batch, upper=zero-fill
// MODE 3: PV   A=Vt[1024][2048],   B=P[2048][2048]; hi-bit complementary pairing (512)
template<int MODE, int KB, int MINW>
__global__ __launch_bounds__(256, MINW)
void gemmQ(const bf16* __restrict__ Abase, const bf16* __restrict__ Bbase,
           const float* __restrict__ bqp, const float* __restrict__ bkp,
           const float* __restrict__ bvp,
           void* __restrict__ o0, void* __restrict__ o1, void* __restrict__ o2)
{
    constexpr int RB  = KB * 2;                // bytes per LDS row
    constexpr int ASZ = 128 * RB;              // A (or B) bytes per K-tile
    constexpr int PST = 2 * ASZ;               // parity stride (A | B)
    __shared__ __align__(16) char smem[2 * PST];

    int m0, n0, nt, z = blockIdx.z;
    const bf16 *Aop, *Bop;
    int lda, ldb;

    if constexpr (MODE == 0) {
        // 1536 blocks: xcd gets contiguous chunk; X n-panel L2-resident per XCD
        const int id = blockIdx.x, xcd = id & 7, r = id >> 3;  // r 0..191
        const int mi = r >> 3;                 // 0..23
        const int ni = xcd * 8 + (r & 7);      // 0..63
        m0 = mi * 128; n0 = ni * 128; nt = DIM / KB;
        Aop = Abase; Bop = Bbase; lda = DIM; ldb = DIM;
    } else if constexpr (MODE == 2) {
        const int u = blockIdx.x;              // 0..255 per batch
        const int qi = u >> 4, ki = u & 15;
        if (ki > qi) {                         // strict-upper tile: zeros only
            float* sc = (float*)o0 + (size_t)z * L_SEQ * L_SEQ;
            const int row = qi * 128 + (threadIdx.x >> 1);
            float* p = sc + (size_t)row * L_SEQ + ki * 128 + (threadIdx.x & 1) * 64;
            f32x4 z4 = {0.f, 0.f, 0.f, 0.f};
#pragma unroll
            for (int c = 0; c < 16; ++c) *(f32x4*)(p + c * 4) = z4;
            return;
        }
        m0 = ki * 128; n0 = qi * 128; nt = DIM / KB;
        Aop = Abase + (size_t)z * L_SEQ * DIM;   // K
        Bop = Bbase + (size_t)z * L_SEQ * DIM;   // Q
        lda = DIM; ldb = DIM;
    } else {
        // 512 blocks; XCD round-robin puts id and id+256 on the SAME CU slot:
        // complement qi across the hi bit -> per-CU K-step sum = 34 = const.
        const int id = blockIdx.x;
        const int hi = id >> 8, lo = id & 255;
        const int q3 = lo >> 5;                  // 0..7
        const int qi = hi ? (15 - q3) : q3;
        const int ei = (lo >> 2) & 7;
        z = lo & 3;
        m0 = ei * 128; n0 = qi * 128; nt = 2 * qi + 2;  // k <= (qi+1)*128 (KB=64 units)
        Aop = Abase + (size_t)z * DIM * L_SEQ;   // Vt
        Bop = Bbase + (size_t)z * L_SEQ * L_SEQ; // P
        lda = L_SEQ; ldb = L_SEQ;
    }

    const int tid  = threadIdx.x;
    const int w    = tid >> 6, lane = tid & 63;
    const int wm   = w >> 1, wn = w & 1;         // 2 (M) x 2 (N) waves
    const int l15  = lane & 15, lh = lane >> 4;
    const int lr4  = lh << 2;

    // staging: linear LDS dest, inverse-swizzled global src (both-sides rule)
    auto stageA = [&](int t) {
#pragma unroll
        for (int s = 0; s < ASZ / 4096; ++s) {
            const int p = s * 4096 + tid * 16;
            int L;
            if constexpr (KB == 64) L = p ^ (((p >> 7) & 7) << 4);
            else                    L = p ^ (((p >> 8) & 3) << 4);
            GLDS(Aop + (size_t)(m0 + (p / RB)) * lda + (t * KB + ((L & (RB - 1)) >> 1)),
                 smem + (t & 1) * PST + (p - (lane << 4)));
        }
    };
    auto stageB = [&](int t) {
#pragma unroll
        for (int s = 0; s < ASZ / 4096; ++s) {
            const int p = s * 4096 + tid * 16;
            int L;
            if constexpr (KB == 64) L = p ^ (((p >> 7) & 7) << 4);
            else                    L = p ^ (((p >> 8) & 3) << 4);
            GLDS(Bop + (size_t)(n0 + (p / RB)) * ldb + (t * KB + ((L & (RB - 1)) >> 1)),
                 smem + (t & 1) * PST + ASZ + (p - (lane << 4)));
        }
    };

    // fragment-read k-offsets (swizzled). KB=64: (row&7)<<4 term = (l15&7)<<4.
    // KB=32: ((row>>2)&3)<<4 term = ((l15>>2)&3)<<4 (rows step by 16 -> lane-const).
    int ko0, ko1 = 0;
    if constexpr (KB == 64) {
        const int swz = (l15 & 7) << 4;
        ko0 = (lh << 4) ^ swz;
        ko1 = (64 + (lh << 4)) ^ swz;
    } else {
        ko0 = (lh << 4) ^ (((l15 >> 2) & 3) << 4);
    }
    const int aro = (wm * 64 + l15) * RB;             // + i*16*RB
    const int bro = ASZ + (wn * 64 + l15) * RB;       // + j*16*RB

    f32x4 acc[4][4];
#pragma unroll
    for (int i = 0; i < 4; ++i)
#pragma unroll
        for (int j = 0; j < 4; ++j) acc[i][j] = (f32x4){0.f, 0.f, 0.f, 0.f};

    // prologue: tiles 0,1 staged; wait tile 0 resident (tile 1's issues flying)
    stageA(0); stageB(0); stageA(1); stageB(1);
    if constexpr (KB == 64) asm volatile("s_waitcnt vmcnt(8)" ::: "memory");
    else                    asm volatile("s_waitcnt vmcnt(4)" ::: "memory");
    __builtin_amdgcn_s_barrier();
    asm volatile("" ::: "memory");

    // 2-barrier K-loop: stage issued under MFMA, counted vmcnt at tile boundary
    for (int t = 0; t < nt; ++t) {
        const bool pref = (t + 2 < nt);
        char* base = smem + (t & 1) * PST;
        bf16x8 af[4][2], bfr[4][2];
#pragma unroll
        for (int i = 0; i < 4; ++i) {
            int ro = aro + i * 16 * RB;
            af[i][0] = *(const bf16x8*)(base + ro + ko0);
            if constexpr (KB == 64) af[i][1] = *(const bf16x8*)(base + ro + ko1);
        }
#pragma unroll
        for (int j = 0; j < 4; ++j) {
            int ro = bro + j * 16 * RB;
            bfr[j][0] = *(const bf16x8*)(base + ro + ko0);
            if constexpr (KB == 64) bfr[j][1] = *(const bf16x8*)(base + ro + ko1);
        }
        asm volatile("s_waitcnt lgkmcnt(0)" ::: "memory");  // own reads done
        __builtin_amdgcn_s_barrier();                        // all waves' reads done
        asm volatile("" ::: "memory");
        if (pref) { stageB(t + 2); stageA(t + 2); }          // overwrite safe; fly under MFMA
        __builtin_amdgcn_s_setprio(1);
#pragma unroll
        for (int i = 0; i < 4; ++i)
#pragma unroll
            for (int j = 0; j < 4; ++j) {
                acc[i][j] = MFMA16(af[i][0], bfr[j][0], acc[i][j], 0, 0, 0);
                if constexpr (KB == 64)
                    acc[i][j] = MFMA16(af[i][1], bfr[j][1], acc[i][j], 0, 0, 0);
            }
        __builtin_amdgcn_s_setprio(0);
        if (pref) {
            if constexpr (KB == 64) asm volatile("s_waitcnt vmcnt(8)" ::: "memory");
            else                    asm volatile("s_waitcnt vmcnt(4)" ::: "memory");
        } else if (t + 1 < nt) {
            asm volatile("s_waitcnt vmcnt(0)" ::: "memory");
        }
        BARX();
    }

    // ---- epilogue: D frag = 4 consecutive M rows (lh*4+r), N col = l15 ----
    if constexpr (MODE == 0) {
        const int sel = m0 >> 10;                 // 0:Q 1:K 2:V (uniform; 128 | 1024)
        const int eb  = (m0 & 1023) + wm * 64;
        if (sel < 2) {
            bf16* out = sel == 0 ? (bf16*)o0 : (bf16*)o1;
            const float* bias = sel == 0 ? bqp : bkp;
#pragma unroll
            for (int i = 0; i < 4; ++i) {
                int e0 = eb + i * 16 + lr4;
                float4 bb = *(const float4*)(bias + e0);
#pragma unroll
                for (int j = 0; j < 4; ++j) {
                    int l = n0 + wn * 64 + j * 16 + l15;
                    bf16x4 v = { (bf16)(acc[i][j][0] + bb.x), (bf16)(acc[i][j][1] + bb.y),
                                 (bf16)(acc[i][j][2] + bb.z), (bf16)(acc[i][j][3] + bb.w) };
                    *(bf16x4*)((bf16*)out + (size_t)l * DIM + e0) = v;
                }
            }
        } else {
            bf16* Vt = (bf16*)o2;
#pragma unroll
            for (int i = 0; i < 4; ++i) {
                int e0 = eb + i * 16 + lr4;
                float4 bb = *(const float4*)(bvp + e0);
                float bbr[4] = { bb.x, bb.y, bb.z, bb.w };
#pragma unroll
                for (int j = 0; j < 4; ++j) {
                    int lg = n0 + wn * 64 + j * 16 + l15;
                    int b = lg >> 11, l = lg & 2047;
#pragma unroll
                    for (int r = 0; r < 4; ++r)
                        Vt[((size_t)b * DIM + e0 + r) * L_SEQ + l] = (bf16)(acc[i][j][r] + bbr[r]);
                }
            }
        }
    } else if constexpr (MODE == 2) {
        float* sc = (float*)o0 + (size_t)z * L_SEQ * L_SEQ;
#pragma unroll
        for (int i = 0; i < 4; ++i) {
            int k0e = m0 + wm * 64 + i * 16 + lr4;
#pragma unroll
            for (int j = 0; j < 4; ++j) {
                int q = n0 + wn * 64 + j * 16 + l15;
                f32x4 v = acc[i][j] * 0.03125f;
                *(f32x4*)(sc + (size_t)q * L_SEQ + k0e) = v;
            }
        }
    } else {
        float* o = (float*)o0 + (size_t)z * L_SEQ * DIM;
#pragma unroll
        for (int i = 0; i < 4; ++i) {
            int e0 = m0 + wm * 64 + i * 16 + lr4;
#pragma unroll
            for (int j = 0; j < 4; ++j) {
                int q = n0 + wn * 64 + j * 16 + l15;
                *(f32x4*)(o + (size_t)q * DIM + e0) = acc[i][j];
            }
        }
    }
}

// ---------------- causal row softmax: 2048 blocks x 4 rows (grid-stride) ----------------
// wts fp32 in-place + bf16 copy (guarded: PV reads only k <= (q|127))
__global__ __launch_bounds__(256)
void softmax_rows(float* __restrict__ wts, bf16* __restrict__ Pb)
{
    const int t = threadIdx.x;
    const int lane = t & 63, w = t >> 6;
    const int k0 = t * 8;
    __shared__ float redm[4], reds[4];

    for (int row = blockIdx.x; row < 8192; row += 2048) {
        const int q = row & 2047;
        float* s = wts + (size_t)row * L_SEQ;
        bf16*  p = Pb  + (size_t)row * L_SEQ;

        float v[8];
        if (k0 + 7 <= q) {
            float4 a = *(const float4*)(s + k0);
            float4 b = *(const float4*)(s + k0 + 4);
            v[0]=a.x; v[1]=a.y; v[2]=a.z; v[3]=a.w;
            v[4]=b.x; v[5]=b.y; v[6]=b.z; v[7]=b.w;
        } else {
#pragma unroll
            for (int c = 0; c < 8; ++c) {
                int k = k0 + c;
                v[c] = (k <= q) ? s[k] : -3.0e38f;
            }
        }

        float mx = v[0];
#pragma unroll
        for (int c = 1; c < 8; ++c) mx = fmaxf(mx, v[c]);
#pragma unroll
        for (int off = 32; off; off >>= 1) mx = fmaxf(mx, __shfl_xor(mx, off));
        if (lane == 0) redm[w] = mx;
        __syncthreads();
        mx = fmaxf(fmaxf(redm[0], redm[1]), fmaxf(redm[2], redm[3]));

        float sm = 0.f;
#pragma unroll
        for (int c = 0; c < 8; ++c) {
            float e = __expf(v[c] - mx);             // masked -> 0 exactly
            v[c] = e;
            sm += e;
        }
#pragma unroll
        for (int off = 32; off; off >>= 1) sm += __shfl_xor(sm, off);
        if (lane == 0) reds[w] = sm;
        __syncthreads();
        sm = reds[0] + reds[1] + reds[2] + reds[3];
        const float inv = 1.f / sm;

        if (k0 <= (q | 127)) {                       // beyond diag tile: pre-zeroed
            float o[8];
#pragma unroll
            for (int c = 0; c < 8; ++c) o[c] = v[c] * inv;
            float4 s0 = { o[0], o[1], o[2], o[3] };
            float4 s1 = { o[4], o[5], o[6], o[7] };
            *(float4*)(s + k0)     = s0;
            *(float4*)(s + k0 + 4) = s1;
            bf16x8 pb = { (bf16)o[0], (bf16)o[1], (bf16)o[2], (bf16)o[3],
                          (bf16)o[4], (bf16)o[5], (bf16)o[6], (bf16)o[7] };
            *(bf16x8*)(p + k0) = pb;
        }
        __syncthreads();                              // redm/reds reuse across rows
    }
}

extern "C" void kernel_launch(void* const* d_in, const int* in_sizes, int n_in,
                              void* d_out, int out_size, void* d_ws, size_t ws_size,
                              hipStream_t stream)
{
    const float* x  = (const float*)d_in[0];
    const float* Wq = (const float*)d_in[1];
    const float* bq = (const float*)d_in[2];
    const float* Wk = (const float*)d_in[3];
    const float* bk = (const float*)d_in[4];
    const float* Wv = (const float*)d_in[5];
    const float* bv = (const float*)d_in[6];

    float* out = (float*)d_out;                               // [4][2048][1024]
    float* wts = out + (size_t)BATCH * L_SEQ * DIM;           // [4][2048][2048]

    char* ws = (char*)d_ws;
    bf16* Xb   = (bf16*)(ws + 0);                  // 16 MiB  [8192][1024]
    bf16* Wcat = (bf16*)(ws + (16u  << 20));       //  6 MiB  [3072][1024]
    bf16* Qb   = (bf16*)(ws + (22u  << 20));       // 16 MiB  [b][l][e]
    bf16* Kb   = (bf16*)(ws + (38u  << 20));       // 16 MiB  [b][l][e]
    bf16* Vt   = (bf16*)(ws + (54u  << 20));       // 16 MiB  [b][e][l]
    bf16* Pb   = (bf16*)(ws + (70u  << 20));       // 32 MiB  [b][q][k]

    cvt_all<<<dim3(2048), dim3(256), 0, stream>>>(x, Wq, Wk, Wv, Xb, Wcat);

    gemmQ<0, 32, 5><<<dim3(1536, 1, 1), dim3(256), 0, stream>>>(
        Wcat, Xb, bq, bk, bv, Qb, Kb, Vt);
    gemmQ<2, 64, 2><<<dim3(256, 1, 4), dim3(256), 0, stream>>>(
        Kb, Qb, nullptr, nullptr, nullptr, wts, nullptr, nullptr);
    softmax_rows<<<dim3(2048), dim3(256), 0, stream>>>(wts, Pb);
    gemmQ<3, 64, 2><<<dim3(512, 1, 1), dim3(256), 0, stream>>>(
        Vt, Pb, nullptr, nullptr, nullptr, out, nullptr, nullptr);
}

// Round 18
// 157.927 us; speedup vs baseline: 1.9684x; 1.9684x over previous
//
#include <hip/hip_runtime.h>
#include <hip/hip_bf16.h>
#include <stdint.h>

#define BATCH 4
#define L_SEQ 2048
#define DIM   1024

typedef __bf16 bf16;
typedef __bf16 bf16x4 __attribute__((ext_vector_type(4)));
typedef __bf16 bf16x8 __attribute__((ext_vector_type(8)));
typedef float  f32x4  __attribute__((ext_vector_type(4)));

#define GLDS(src, dst) __builtin_amdgcn_global_load_lds(\
    (const __attribute__((address_space(1))) void*)(src), \
    (__attribute__((address_space(3))) void*)(dst), 16, 0, 0)

// barrier with memory-clobber only (no sched_barrier: m141 lesson)
#define BARX() do { asm volatile("" ::: "memory"); \
                    __builtin_amdgcn_s_barrier(); \
                    asm volatile("" ::: "memory"); } while (0)

#define MFMA16 __builtin_amdgcn_mfma_f32_16x16x32_bf16

// ---------------- fused fp32 -> bf16 convert, grid-stride (2048 blocks) ----------------
__global__ __launch_bounds__(256)
void cvt_all(const float* __restrict__ x,  const float* __restrict__ Wq,
             const float* __restrict__ Wk, const float* __restrict__ Wv,
             bf16* __restrict__ Xb, bf16* __restrict__ Wcat)
{
    for (int b = blockIdx.x; b < 11264; b += 2048) {
        const float* src; bf16* dst; int i;
        if (b < 8192) { src = x; dst = Xb; i = b * 256 + threadIdx.x; }
        else {
            int s = (b - 8192) >> 10;
            src = s == 0 ? Wq : (s == 1 ? Wk : Wv);
            dst = Wcat + (size_t)s * 1048576;
            i = ((b - 8192) & 1023) * 256 + threadIdx.x;
        }
        float4 v = ((const float4*)src)[i];
        bf16x4 o = { (bf16)v.x, (bf16)v.y, (bf16)v.z, (bf16)v.w };
        ((bf16x4*)dst)[i] = o;
    }
}

// ---- 128x128-tile, BK=64, 4 waves (2x2, 64x64/wave), 2-barrier counted-vmcnt ----
// 64 KB LDS -> 2 blocks/CU: cross-block overlap hides barrier/load stalls.
// A[m][k], B[n][k], K-contiguous; C = A*B^T fp32; A-dim contiguous in output.
// MODE 0: QKV  A=Wcat[3072][1024], B=X[8192][1024]; XCD-chunked grid (1536)
// MODE 2: SC   A=K[2048][1024],    B=Q[2048][1024]; 16x16 tile grid/batch, upper=zero-fill
// MODE 3: PV   A=Vt[1024][2048],   B=P[2048][2048]; hi-bit complementary pairing (512)
template<int MODE>
__global__ __launch_bounds__(256, 2)
void gemmQ(const bf16* __restrict__ Abase, const bf16* __restrict__ Bbase,
           const float* __restrict__ bqp, const float* __restrict__ bkp,
           const float* __restrict__ bvp,
           void* __restrict__ o0, void* __restrict__ o1, void* __restrict__ o2)
{
    constexpr int PST = 32768;                 // A 16K | B 16K per parity
    __shared__ __align__(16) char smem[65536];

    int m0, n0, nt, z = blockIdx.z;
    const bf16 *Aop, *Bop;
    int lda, ldb;

    if constexpr (MODE == 0) {
        // 1536 blocks: xcd gets contiguous chunk; X n-panel L2-resident per XCD
        const int id = blockIdx.x, xcd = id & 7, r = id >> 3;  // r 0..191
        const int mi = r >> 3;                 // 0..23
        const int ni = xcd * 8 + (r & 7);      // 0..63
        m0 = mi * 128; n0 = ni * 128; nt = 16;
        Aop = Abase; Bop = Bbase; lda = DIM; ldb = DIM;
    } else if constexpr (MODE == 2) {
        const int u = blockIdx.x;              // 0..255 per batch
        const int qi = u >> 4, ki = u & 15;
        if (ki > qi) {                         // strict-upper tile: zeros only
            float* sc = (float*)o0 + (size_t)z * L_SEQ * L_SEQ;
            const int row = qi * 128 + (threadIdx.x >> 1);
            float* p = sc + (size_t)row * L_SEQ + ki * 128 + (threadIdx.x & 1) * 64;
            f32x4 z4 = {0.f, 0.f, 0.f, 0.f};
#pragma unroll
            for (int c = 0; c < 16; ++c) *(f32x4*)(p + c * 4) = z4;
            return;
        }
        m0 = ki * 128; n0 = qi * 128; nt = 16;
        Aop = Abase + (size_t)z * L_SEQ * DIM;   // K
        Bop = Bbase + (size_t)z * L_SEQ * DIM;   // Q
        lda = DIM; ldb = DIM;
    } else {
        // 512 blocks; XCD round-robin puts id and id+256 on the SAME CU slot:
        // complement qi across the hi bit -> per-CU K-step sum = 34 = const.
        const int id = blockIdx.x;
        const int hi = id >> 8, lo = id & 255;
        const int q3 = lo >> 5;                  // 0..7
        const int qi = hi ? (15 - q3) : q3;
        const int ei = (lo >> 2) & 7;
        z = lo & 3;
        m0 = ei * 128; n0 = qi * 128; nt = 2 * qi + 2;  // k <= (qi+1)*128
        Aop = Abase + (size_t)z * DIM * L_SEQ;   // Vt
        Bop = Bbase + (size_t)z * L_SEQ * L_SEQ; // P
        lda = L_SEQ; ldb = L_SEQ;
    }

    const int tid  = threadIdx.x;
    const int w    = tid >> 6, lane = tid & 63;
    const int wm   = w >> 1, wn = w & 1;         // 2 (M) x 2 (N) waves
    const int l15  = lane & 15, lh = lane >> 4;
    const int lr4  = lh << 2;

    // staging: linear LDS dest, inverse-swizzled global src (both-sides rule)
    auto stageA = [&](int t) {
#pragma unroll
        for (int s = 0; s < 4; ++s) {
            const int p = s * 4096 + tid * 16;
            const int L = p ^ (((p >> 7) & 7) << 4);
            GLDS(Aop + (size_t)(m0 + (p >> 7)) * lda + ((t << 6) + ((L & 127) >> 1)),
                 smem + (t & 1) * PST + (p - (lane << 4)));
        }
    };
    auto stageB = [&](int t) {
#pragma unroll
        for (int s = 0; s < 4; ++s) {
            const int p = s * 4096 + tid * 16;
            const int L = p ^ (((p >> 7) & 7) << 4);
            GLDS(Bop + (size_t)(n0 + (p >> 7)) * ldb + ((t << 6) + ((L & 127) >> 1)),
                 smem + (t & 1) * PST + 16384 + (p - (lane << 4)));
        }
    };

    // fragment reads: XOR-swizzle (row&7)<<4 on 128-B rows
    const int swz = (l15 & 7) << 4;
    const int ko0 = (lh << 4) ^ swz;
    const int ko1 = (64 + (lh << 4)) ^ swz;
    const int aro = (wm * 64 + l15) * 128;            // + i*2048
    const int bro = 16384 + (wn * 64 + l15) * 128;    // + j*2048

    f32x4 acc[4][4];
#pragma unroll
    for (int i = 0; i < 4; ++i)
#pragma unroll
        for (int j = 0; j < 4; ++j) acc[i][j] = (f32x4){0.f, 0.f, 0.f, 0.f};

    // prologue: tiles 0,1 staged (16 issues); wait tile 0 resident (8 left flying)
    stageA(0); stageB(0); stageA(1); stageB(1);
    asm volatile("s_waitcnt vmcnt(8)" ::: "memory");
    __builtin_amdgcn_s_barrier();
    asm volatile("" ::: "memory");

    // 2-barrier K-loop: 32 MFMA per barrier-pair, stage issued under MFMA
    for (int t = 0; t < nt; ++t) {
        const bool pref = (t + 2 < nt);
        char* base = smem + (t & 1) * PST;
        bf16x8 af[4][2], bfr[4][2];
#pragma unroll
        for (int i = 0; i < 4; ++i) {
            int ro = aro + i * 2048;
            af[i][0] = *(const bf16x8*)(base + ro + ko0);
            af[i][1] = *(const bf16x8*)(base + ro + ko1);
        }
#pragma unroll
        for (int j = 0; j < 4; ++j) {
            int ro = bro + j * 2048;
            bfr[j][0] = *(const bf16x8*)(base + ro + ko0);
            bfr[j][1] = *(const bf16x8*)(base + ro + ko1);
        }
        asm volatile("s_waitcnt lgkmcnt(0)" ::: "memory");  // own reads done
        __builtin_amdgcn_s_barrier();                        // all waves' reads done
        asm volatile("" ::: "memory");
        if (pref) { stageB(t + 2); stageA(t + 2); }          // overwrite safe; fly under MFMA
        __builtin_amdgcn_s_setprio(1);
#pragma unroll
        for (int i = 0; i < 4; ++i)
#pragma unroll
            for (int j = 0; j < 4; ++j) {
                acc[i][j] = MFMA16(af[i][0], bfr[j][0], acc[i][j], 0, 0, 0);
                acc[i][j] = MFMA16(af[i][1], bfr[j][1], acc[i][j], 0, 0, 0);
            }
        __builtin_amdgcn_s_setprio(0);
        if (pref)            asm volatile("s_waitcnt vmcnt(8)" ::: "memory"); // t+1 resident
        else if (t + 1 < nt) asm volatile("s_waitcnt vmcnt(0)" ::: "memory");
        BARX();
    }

    // ---- epilogue: D frag = 4 consecutive M rows (lh*4+r), N col = l15 ----
    if constexpr (MODE == 0) {
        const int sel = m0 >> 10;                 // 0:Q 1:K 2:V (uniform; 128 | 1024)
        const int eb  = (m0 & 1023) + wm * 64;
        if (sel < 2) {
            bf16* out = sel == 0 ? (bf16*)o0 : (bf16*)o1;
            const float* bias = sel == 0 ? bqp : bkp;
#pragma unroll
            for (int i = 0; i < 4; ++i) {
                int e0 = eb + i * 16 + lr4;
                float4 bb = *(const float4*)(bias + e0);
#pragma unroll
                for (int j = 0; j < 4; ++j) {
                    int l = n0 + wn * 64 + j * 16 + l15;
                    bf16x4 v = { (bf16)(acc[i][j][0] + bb.x), (bf16)(acc[i][j][1] + bb.y),
                                 (bf16)(acc[i][j][2] + bb.z), (bf16)(acc[i][j][3] + bb.w) };
                    *(bf16x4*)((bf16*)out + (size_t)l * DIM + e0) = v;
                }
            }
        } else {
            bf16* Vt = (bf16*)o2;
#pragma unroll
            for (int i = 0; i < 4; ++i) {
                int e0 = eb + i * 16 + lr4;
                float4 bb = *(const float4*)(bvp + e0);
                float bbr[4] = { bb.x, bb.y, bb.z, bb.w };
#pragma unroll
                for (int j = 0; j < 4; ++j) {
                    int lg = n0 + wn * 64 + j * 16 + l15;
                    int b = lg >> 11, l = lg & 2047;
#pragma unroll
                    for (int r = 0; r < 4; ++r)
                        Vt[((size_t)b * DIM + e0 + r) * L_SEQ + l] = (bf16)(acc[i][j][r] + bbr[r]);
                }
            }
        }
    } else if constexpr (MODE == 2) {
        float* sc = (float*)o0 + (size_t)z * L_SEQ * L_SEQ;
#pragma unroll
        for (int i = 0; i < 4; ++i) {
            int k0e = m0 + wm * 64 + i * 16 + lr4;
#pragma unroll
            for (int j = 0; j < 4; ++j) {
                int q = n0 + wn * 64 + j * 16 + l15;
                f32x4 v = acc[i][j] * 0.03125f;
                *(f32x4*)(sc + (size_t)q * L_SEQ + k0e) = v;
            }
        }
    } else {
        float* o = (float*)o0 + (size_t)z * L_SEQ * DIM;
#pragma unroll
        for (int i = 0; i < 4; ++i) {
            int e0 = m0 + wm * 64 + i * 16 + lr4;
#pragma unroll
            for (int j = 0; j < 4; ++j) {
                int q = n0 + wn * 64 + j * 16 + l15;
                *(f32x4*)(o + (size_t)q * DIM + e0) = acc[i][j];
            }
        }
    }
}

// ---------------- causal row softmax: 2048 blocks x 4 rows (grid-stride) ----------------
// wts fp32 in-place + bf16 copy (guarded: PV reads only k <= (q|127))
__global__ __launch_bounds__(256)
void softmax_rows(float* __restrict__ wts, bf16* __restrict__ Pb)
{
    const int t = threadIdx.x;
    const int lane = t & 63, w = t >> 6;
    const int k0 = t * 8;
    __shared__ float redm[4], reds[4];

    for (int row = blockIdx.x; row < 8192; row += 2048) {
        const int q = row & 2047;
        float* s = wts + (size_t)row * L_SEQ;
        bf16*  p = Pb  + (size_t)row * L_SEQ;

        float v[8];
        if (k0 + 7 <= q) {
            float4 a = *(const float4*)(s + k0);
            float4 b = *(const float4*)(s + k0 + 4);
            v[0]=a.x; v[1]=a.y; v[2]=a.z; v[3]=a.w;
            v[4]=b.x; v[5]=b.y; v[6]=b.z; v[7]=b.w;
        } else {
#pragma unroll
            for (int c = 0; c < 8; ++c) {
                int k = k0 + c;
                v[c] = (k <= q) ? s[k] : -3.0e38f;
            }
        }

        float mx = v[0];
#pragma unroll
        for (int c = 1; c < 8; ++c) mx = fmaxf(mx, v[c]);
#pragma unroll
        for (int off = 32; off; off >>= 1) mx = fmaxf(mx, __shfl_xor(mx, off));
        if (lane == 0) redm[w] = mx;
        __syncthreads();
        mx = fmaxf(fmaxf(redm[0], redm[1]), fmaxf(redm[2], redm[3]));

        float sm = 0.f;
#pragma unroll
        for (int c = 0; c < 8; ++c) {
            float e = __expf(v[c] - mx);             // masked -> 0 exactly
            v[c] = e;
            sm += e;
        }
#pragma unroll
        for (int off = 32; off; off >>= 1) sm += __shfl_xor(sm, off);
        if (lane == 0) reds[w] = sm;
        __syncthreads();
        sm = reds[0] + reds[1] + reds[2] + reds[3];
        const float inv = 1.f / sm;

        if (k0 <= (q | 127)) {                       // beyond diag tile: pre-zeroed
            float o[8];
#pragma unroll
            for (int c = 0; c < 8; ++c) o[c] = v[c] * inv;
            float4 s0 = { o[0], o[1], o[2], o[3] };
            float4 s1 = { o[4], o[5], o[6], o[7] };
            *(float4*)(s + k0)     = s0;
            *(float4*)(s + k0 + 4) = s1;
            bf16x8 pb = { (bf16)o[0], (bf16)o[1], (bf16)o[2], (bf16)o[3],
                          (bf16)o[4], (bf16)o[5], (bf16)o[6], (bf16)o[7] };
            *(bf16x8*)(p + k0) = pb;
        }
        __syncthreads();                              // redm/reds reuse across rows
    }
}

extern "C" void kernel_launch(void* const* d_in, const int* in_sizes, int n_in,
                              void* d_out, int out_size, void* d_ws, size_t ws_size,
                              hipStream_t stream)
{
    const float* x  = (const float*)d_in[0];
    const float* Wq = (const float*)d_in[1];
    const float* bq = (const float*)d_in[2];
    const float* Wk = (const float*)d_in[3];
    const float* bk = (const float*)d_in[4];
    const float* Wv = (const float*)d_in[5];
    const float* bv = (const float*)d_in[6];

    float* out = (float*)d_out;                               // [4][2048][1024]
    float* wts = out + (size_t)BATCH * L_SEQ * DIM;           // [4][2048][2048]

    char* ws = (char*)d_ws;
    bf16* Xb   = (bf16*)(ws + 0);                  // 16 MiB  [8192][1024]
    bf16* Wcat = (bf16*)(ws + (16u  << 20));       //  6 MiB  [3072][1024]
    bf16* Qb   = (bf16*)(ws + (22u  << 20));       // 16 MiB  [b][l][e]
    bf16* Kb   = (bf16*)(ws + (38u  << 20));       // 16 MiB  [b][l][e]
    bf16* Vt   = (bf16*)(ws + (54u  << 20));       // 16 MiB  [b][e][l]
    bf16* Pb   = (bf16*)(ws + (70u  << 20));       // 32 MiB  [b][q][k]

    cvt_all<<<dim3(2048), dim3(256), 0, stream>>>(x, Wq, Wk, Wv, Xb, Wcat);

    gemmQ<0><<<dim3(1536, 1, 1), dim3(256), 0, stream>>>(
        Wcat, Xb, bq, bk, bv, Qb, Kb, Vt);
    gemmQ<2><<<dim3(256, 1, 4), dim3(256), 0, stream>>>(
        Kb, Qb, nullptr, nullptr, nullptr, wts, nullptr, nullptr);
    softmax_rows<<<dim3(2048), dim3(256), 0, stream>>>(wts, Pb);
    gemmQ<3><<<dim3(512, 1, 1), dim3(256), 0, stream>>>(
        Vt, Pb, nullptr, nullptr, nullptr, out, nullptr, nullptr);
}